// Round 1
// baseline (422.618 us; speedup 1.0000x reference)
//
#include <hip/hip_runtime.h>

#define BM 64          // rows per block
#define KC 64          // K chunk staged in LDS
#define DD 2048        // d_model
#define EE 64          // experts
#define NROWS 32768    // 4 * 8192

// ---------------------------------------------------------------------------
// Main kernel: logits GEMM (64 rows x 64 experts per block) + top-2 softmax
// epilogue + block-local router-prob column sums -> global atomic accumulate.
// ---------------------------------------------------------------------------
__global__ __launch_bounds__(256) void router_main(const float* __restrict__ x,
                                                   const float* __restrict__ W,
                                                   float* __restrict__ out,
                                                   float* __restrict__ accum) {
    __shared__ float xs[KC][BM];       // x tile, transposed: xs[k][row]
    __shared__ float ws[KC][EE];       // W tile, transposed: ws[k][expert]
    __shared__ float lg[BM][EE + 1];   // logits gather (+1 pad vs bank conflicts)
    __shared__ float rowinv[BM];

    const int t = threadIdx.x;
    const int row0 = blockIdx.x * BM;

    // micro-tile mapping: 16 row-groups x 16 expert-groups of 4
    const int tr = t & 15;    // row group   -> rows  4*tr .. 4*tr+3
    const int tc = t >> 4;    // expert group-> exps  4*tc .. 4*tc+3

    // staging mapping: 64 rows x 4 k-quads
    const int lrow = t >> 2;        // 0..63 (row for x, expert for W)
    const int lk4  = (t & 3) * 4;   // 0,4,8,12

    float acc[4][4];
#pragma unroll
    for (int i = 0; i < 4; ++i)
#pragma unroll
        for (int j = 0; j < 4; ++j) acc[i][j] = 0.f;

    for (int kb = 0; kb < DD; kb += KC) {
        // stage x tile (transpose on the way in)
#pragma unroll
        for (int c = 0; c < 4; ++c) {
            const int k = lk4 + c * 16;
            const float4 v = *reinterpret_cast<const float4*>(
                &x[(size_t)(row0 + lrow) * DD + kb + k]);
            xs[k + 0][lrow] = v.x;
            xs[k + 1][lrow] = v.y;
            xs[k + 2][lrow] = v.z;
            xs[k + 3][lrow] = v.w;
        }
        // stage W tile (transpose)
#pragma unroll
        for (int c = 0; c < 4; ++c) {
            const int k = lk4 + c * 16;
            const float4 v = *reinterpret_cast<const float4*>(
                &W[(size_t)lrow * DD + kb + k]);
            ws[k + 0][lrow] = v.x;
            ws[k + 1][lrow] = v.y;
            ws[k + 2][lrow] = v.z;
            ws[k + 3][lrow] = v.w;
        }
        __syncthreads();

#pragma unroll
        for (int k = 0; k < KC; ++k) {
            const float4 xa = *reinterpret_cast<const float4*>(&xs[k][tr * 4]);
            const float4 wv = *reinterpret_cast<const float4*>(&ws[k][tc * 4]);
            acc[0][0] = fmaf(xa.x, wv.x, acc[0][0]);
            acc[0][1] = fmaf(xa.x, wv.y, acc[0][1]);
            acc[0][2] = fmaf(xa.x, wv.z, acc[0][2]);
            acc[0][3] = fmaf(xa.x, wv.w, acc[0][3]);
            acc[1][0] = fmaf(xa.y, wv.x, acc[1][0]);
            acc[1][1] = fmaf(xa.y, wv.y, acc[1][1]);
            acc[1][2] = fmaf(xa.y, wv.z, acc[1][2]);
            acc[1][3] = fmaf(xa.y, wv.w, acc[1][3]);
            acc[2][0] = fmaf(xa.z, wv.x, acc[2][0]);
            acc[2][1] = fmaf(xa.z, wv.y, acc[2][1]);
            acc[2][2] = fmaf(xa.z, wv.z, acc[2][2]);
            acc[2][3] = fmaf(xa.z, wv.w, acc[2][3]);
            acc[3][0] = fmaf(xa.w, wv.x, acc[3][0]);
            acc[3][1] = fmaf(xa.w, wv.y, acc[3][1]);
            acc[3][2] = fmaf(xa.w, wv.z, acc[3][2]);
            acc[3][3] = fmaf(xa.w, wv.w, acc[3][3]);
        }
        __syncthreads();
    }

    // gather logits into LDS
#pragma unroll
    for (int i = 0; i < 4; ++i)
#pragma unroll
        for (int j = 0; j < 4; ++j) lg[tr * 4 + i][tc * 4 + j] = acc[i][j];
    __syncthreads();

    // per-row epilogue: top-2 (jax tie-break = lowest index first), softmax
    if (t < BM) {
        const int r = t;
        float m1 = -1e30f, m2 = -1e30f;
        int i1 = 0, i2 = 0;
        for (int e = 0; e < EE; ++e) {
            const float l = lg[r][e];
            if (l > m1) {
                m2 = m1; i2 = i1;
                m1 = l;  i1 = e;
            } else if (l > m2) {
                m2 = l; i2 = e;
            }
        }
        float s = 0.f;
        for (int e = 0; e < EE; ++e) {
            const float p = __expf(lg[r][e] - m1);
            lg[r][e] = p;   // stash exp for column sums
            s += p;
        }
        rowinv[r] = 1.f / s;

        // top-2 softmax: [1/(1+e2), e2/(1+e2)] with e2 = exp(m2-m1)
        const float e2  = __expf(m2 - m1);
        const float inv = 1.f / (1.f + e2);
        const size_t gr = (size_t)row0 + r;
        out[2 * gr]     = inv;
        out[2 * gr + 1] = e2 * inv;
        // indices written as floats (harness reads whole buffer as fp32)
        out[2 * (size_t)NROWS + 2 * gr]     = (float)i1;
        out[2 * (size_t)NROWS + 2 * gr + 1] = (float)i2;
    }
    __syncthreads();

    // column sums of router probs over this block's rows -> one atomic each
    if (t < EE) {
        const int e = t;
        float cs = 0.f;
        for (int r = 0; r < BM; ++r) cs += lg[r][e] * rowinv[r];
        atomicAdd(&accum[e], cs);
    }
}

// ---------------------------------------------------------------------------
// Tiny finisher: expert_probs = accum / NROWS; lb_loss = .01 * sum(p*log(p+1e-8))
// ---------------------------------------------------------------------------
__global__ void router_loss(const float* __restrict__ accum, float* __restrict__ out) {
    const int e = threadIdx.x;  // 64 threads = 1 wave
    const float p = accum[e] * (1.0f / (float)NROWS);
    float v = p * __logf(p + 1e-8f);
#pragma unroll
    for (int off = 32; off > 0; off >>= 1) v += __shfl_down(v, off);
    if (e == 0) out[4 * (size_t)NROWS] = 0.01f * v;
}

extern "C" void kernel_launch(void* const* d_in, const int* in_sizes, int n_in,
                              void* d_out, int out_size, void* d_ws, size_t ws_size,
                              hipStream_t stream) {
    const float* x = (const float*)d_in[0];
    const float* W = (const float*)d_in[1];
    float* out = (float*)d_out;
    float* accum = (float*)d_ws;

    hipMemsetAsync(d_ws, 0, EE * sizeof(float), stream);
    router_main<<<NROWS / BM, 256, 0, stream>>>(x, W, out, accum);
    router_loss<<<1, 64, 0, stream>>>(accum, out);
}